// Round 4
// baseline (127.619 us; speedup 1.0000x reference)
//
#include <hip/hip_runtime.h>
#include <hip/hip_bf16.h>
#include <math.h>

// B=4, H=16, S=1024, P=64, D=1024
// d_in: 0=q [64,1024,64] f32, 1=k, 2=v, 3=w_merge [1024,1024] f32,
//       4=position_mask [1024,1024] bool->int32 (unused; recomputed analytically),
//       5=src_length_mask [4,1024] bool->int32
// d_out: [4,1024,1024] f32

typedef _Float16 f16x8 __attribute__((ext_vector_type(8)));
typedef unsigned short u16x8 __attribute__((ext_vector_type(8)));
typedef float f32x4 __attribute__((ext_vector_type(4)));

union H8 { u16x8 u; f16x8 h; };

static __device__ __forceinline__ unsigned short f2hu(float f) {
  _Float16 h = (_Float16)f;
  unsigned short u;
  __builtin_memcpy(&u, &h, 2);
  return u;
}

#define MFMA16(a, b, c) __builtin_amdgcn_mfma_f32_16x16x32_f16((a), (b), (c), 0, 0, 0)

// ---------------- prep: lengths (int32 mask!) + w_merge fp32->fp16 ----------------
__global__ __launch_bounds__(256) void prep_kernel(const float* __restrict__ w,
                                                   const int* __restrict__ smask,
                                                   unsigned short* __restrict__ w_h,
                                                   int* __restrict__ lengths) {
  const int bid = blockIdx.x;
  const int tid = threadIdx.x;
  if (bid < 4) {
    // count masked (nonzero) int32 entries in row bid -> length = 1024 - count
    __shared__ int sh[256];
    int4 m = ((const int4*)(smask + bid * 1024))[tid];
    sh[tid] = (m.x != 0) + (m.y != 0) + (m.z != 0) + (m.w != 0);
    __syncthreads();
    for (int o = 128; o > 0; o >>= 1) {
      if (tid < o) sh[tid] += sh[tid + o];
      __syncthreads();
    }
    if (tid == 0) lengths[bid] = 1024 - sh[0];
  } else {
    int idx = (bid - 4) * 256 + tid;  // float4 index, total 262144
    float4 f = ((const float4*)w)[idx];
    ushort4 o;
    o.x = f2hu(f.x); o.y = f2hu(f.y); o.z = f2hu(f.z); o.w = f2hu(f.w);
    ((ushort4*)w_h)[idx] = o;
  }
}

// ---------------- flash attention ----------------
// grid: (16 q-tiles, 64 bh); block 256 = 4 waves; wave wv owns q rows [qbase+wv*16, +16)
__global__ __launch_bounds__(256) void attn_kernel(const float* __restrict__ q,
                                                   const float* __restrict__ k,
                                                   const float* __restrict__ v,
                                                   const int* __restrict__ lengths,
                                                   unsigned short* __restrict__ attn_out) {
  const int qt = blockIdx.x;
  const int bh = blockIdx.y;
  const int b = bh >> 4;
  const int h = bh & 15;
  const int tid = threadIdx.x;
  const int lane = tid & 63;
  const int wv = tid >> 6;
  const int l15 = lane & 15;
  const int kgrp = lane >> 4;  // 0..3
  const int qbase = qt * 64;
  const int len = lengths[b];  // >= 512 by construction

  __shared__ unsigned short Klds[64 * 64];      // [s][p], XOR-swizzled
  __shared__ unsigned short Vlds[64 * 64];      // [p][s] (transposed), XOR-swizzled
  __shared__ unsigned short Plds[4][16 * 64];   // per-wave P [row][s], XOR-swizzled

  // Q fragments: A row = l15, k = kgrp*8 + j (+ kb*32)
  H8 qa[2];
  {
    const float* qp = q + ((size_t)bh * 1024 + (qbase + wv * 16 + l15)) * 64;
#pragma unroll
    for (int kb = 0; kb < 2; kb++) {
      const float* p0 = qp + kb * 32 + kgrp * 8;
      float4 f0 = *(const float4*)(p0);
      float4 f1 = *(const float4*)(p0 + 4);
      u16x8 u;
      u[0] = f2hu(f0.x); u[1] = f2hu(f0.y); u[2] = f2hu(f0.z); u[3] = f2hu(f0.w);
      u[4] = f2hu(f1.x); u[5] = f2hu(f1.y); u[6] = f2hu(f1.z); u[7] = f2hu(f1.w);
      qa[kb].u = u;
    }
  }

  f32x4 oacc[4] = {};  // feature cols nb*16+l15, rows kgrp*4+r
  float mrow[4], lrow[4];
#pragma unroll
  for (int r = 0; r < 4; r++) { mrow[r] = -INFINITY; lrow[r] = 0.f; }

  const int cap = (len - 1 < qbase + 63) ? (len - 1) : (qbase + 63);
  const int nkt = (cap >> 6) + 1;

  for (int kt = 0; kt < nkt; ++kt) {
    __syncthreads();
    // ---- stage K (as [s][p]) and V (transposed [p][s]) to LDS as fp16 ----
    const float* kp = k + ((size_t)bh * 1024 + kt * 64) * 64;
    const float* vp = v + ((size_t)bh * 1024 + kt * 64) * 64;
#pragma unroll
    for (int i = 0; i < 4; i++) {
      int e = i * 256 + tid;       // float4 index in 64x64 tile
      int row = e >> 4;            // key position
      int c4 = (e & 15) * 4;       // feature
      float4 f = *(const float4*)(kp + row * 64 + c4);
      ushort4 o;
      o.x = f2hu(f.x); o.y = f2hu(f.y); o.z = f2hu(f.z); o.w = f2hu(f.w);
      *(ushort4*)((char*)Klds + ((row * 128 + c4 * 2) ^ ((row & 7) << 4))) = o;
      float4 g = *(const float4*)(vp + row * 64 + c4);
      *(unsigned short*)((char*)Vlds + (((c4 + 0) * 128 + row * 2) ^ (((c4 + 0) & 7) << 4))) = f2hu(g.x);
      *(unsigned short*)((char*)Vlds + (((c4 + 1) * 128 + row * 2) ^ (((c4 + 1) & 7) << 4))) = f2hu(g.y);
      *(unsigned short*)((char*)Vlds + (((c4 + 2) * 128 + row * 2) ^ (((c4 + 2) & 7) << 4))) = f2hu(g.z);
      *(unsigned short*)((char*)Vlds + (((c4 + 3) * 128 + row * 2) ^ (((c4 + 3) & 7) << 4))) = f2hu(g.w);
    }
    __syncthreads();

    // ---- S = Q K^T ----
    f32x4 sacc[4] = {};
#pragma unroll
    for (int kb = 0; kb < 2; kb++) {
#pragma unroll
      for (int nb = 0; nb < 4; nb++) {
        int srow = nb * 16 + l15;  // key position (B col n)
        H8 bb;
        bb.u = *(const u16x8*)((const char*)Klds +
                               ((srow * 128 + (kb * 32 + kgrp * 8) * 2) ^ ((srow & 7) << 4)));
        sacc[nb] = MFMA16(qa[kb].h, bb.h, sacc[nb]);
      }
    }

    // ---- scale + mask ----
#pragma unroll
    for (int nb = 0; nb < 4; nb++) {
      int scol = kt * 64 + nb * 16 + l15;
#pragma unroll
      for (int r = 0; r < 4; r++) {
        int trow = qbase + wv * 16 + kgrp * 4 + r;
        float sv = sacc[nb][r] * 0.125f;
        sacc[nb][r] = (scol > trow || scol >= len) ? -INFINITY : sv;
      }
    }

    // ---- online softmax (rows live in 16-lane groups) ----
    float tmax[4];
#pragma unroll
    for (int r = 0; r < 4; r++)
      tmax[r] = fmaxf(fmaxf(sacc[0][r], sacc[1][r]), fmaxf(sacc[2][r], sacc[3][r]));
#pragma unroll
    for (int d = 1; d < 16; d <<= 1) {
#pragma unroll
      for (int r = 0; r < 4; r++) tmax[r] = fmaxf(tmax[r], __shfl_xor(tmax[r], d));
    }
    float alpha[4], psum[4];
#pragma unroll
    for (int r = 0; r < 4; r++) {
      float mnew = fmaxf(mrow[r], tmax[r]);
      alpha[r] = __expf(mrow[r] - mnew);  // first tile: exp(-inf) = 0
      mrow[r] = mnew;
      psum[r] = 0.f;
    }
#pragma unroll
    for (int nb = 0; nb < 4; nb++) {
#pragma unroll
      for (int r = 0; r < 4; r++) {
        float pv = __expf(sacc[nb][r] - mrow[r]);  // masked -inf -> 0
        psum[r] += pv;
        sacc[nb][r] = pv;
      }
    }
#pragma unroll
    for (int d = 1; d < 16; d <<= 1) {
#pragma unroll
      for (int r = 0; r < 4; r++) psum[r] += __shfl_xor(psum[r], d);
    }
#pragma unroll
    for (int r = 0; r < 4; r++) lrow[r] = lrow[r] * alpha[r] + psum[r];

    // rescale O, write P (fp16) to wave-private LDS
#pragma unroll
    for (int nb = 0; nb < 4; nb++) {
#pragma unroll
      for (int r = 0; r < 4; r++) oacc[nb][r] *= alpha[r];
#pragma unroll
      for (int r = 0; r < 4; r++) {
        int prow = kgrp * 4 + r;
        int pcol = nb * 16 + l15;
        *(unsigned short*)((char*)(&Plds[wv][0]) +
                           ((prow * 128 + pcol * 2) ^ ((prow & 7) << 4))) = f2hu(sacc[nb][r]);
      }
    }

    // ---- O += P V ----
#pragma unroll
    for (int kb = 0; kb < 2; kb++) {
      H8 pa;
      pa.u = *(const u16x8*)((const char*)(&Plds[wv][0]) +
                             ((l15 * 128 + (kb * 32 + kgrp * 8) * 2) ^ ((l15 & 7) << 4)));
#pragma unroll
      for (int nb = 0; nb < 4; nb++) {
        int feat = nb * 16 + l15;
        H8 vb;
        vb.u = *(const u16x8*)((const char*)Vlds +
                               ((feat * 128 + (kb * 32 + kgrp * 8) * 2) ^ ((feat & 7) << 4)));
        oacc[nb] = MFMA16(pa.h, vb.h, oacc[nb]);
      }
    }
  }

  // ---- epilogue: divide by l, store merged-head layout [b][t][h*64+p] as fp16 ----
#pragma unroll
  for (int nb = 0; nb < 4; nb++) {
#pragma unroll
    for (int r = 0; r < 4; r++) {
      float outv = oacc[nb][r] / lrow[r];
      int trow = qbase + wv * 16 + kgrp * 4 + r;
      int feat = nb * 16 + l15;
      attn_out[((size_t)b * 1024 + trow) * 1024 + h * 64 + feat] = f2hu(outv);
    }
  }
}

// ---------------- merge GEMM: out[4096,1024] = A[4096,1024] @ W^T ----------------
// B[k][n] = w[n][k]: w_merge row-major already matches (read row n, contiguous k).
__global__ __launch_bounds__(256) void merge_kernel(const unsigned short* __restrict__ a_h,
                                                    const unsigned short* __restrict__ w_h,
                                                    float* __restrict__ out) {
  const int n0 = blockIdx.x * 64;
  const int m0 = blockIdx.y * 64;
  const int tid = threadIdx.x;
  const int lane = tid & 63;
  const int wv = tid >> 6;
  const int l15 = lane & 15;
  const int kgrp = lane >> 4;

  __shared__ unsigned short Alds[64 * 64];
  __shared__ unsigned short Wlds[64 * 64];

  f32x4 acc[4] = {};

  for (int kt = 0; kt < 16; ++kt) {
    __syncthreads();
#pragma unroll
    for (int i = 0; i < 4; i++) {
      int e = i * 256 + tid;     // ushort4 index
      int row = e >> 4;
      int c4 = (e & 15) * 4;
      ushort4 av = *(const ushort4*)(a_h + (size_t)(m0 + row) * 1024 + kt * 64 + c4);
      *(ushort4*)((char*)Alds + ((row * 128 + c4 * 2) ^ ((row & 7) << 4))) = av;
      ushort4 wv4 = *(const ushort4*)(w_h + (size_t)(n0 + row) * 1024 + kt * 64 + c4);
      *(ushort4*)((char*)Wlds + ((row * 128 + c4 * 2) ^ ((row & 7) << 4))) = wv4;
    }
    __syncthreads();
#pragma unroll
    for (int kb = 0; kb < 2; kb++) {
      int arow = wv * 16 + l15;
      H8 aa;
      aa.u = *(const u16x8*)((const char*)Alds +
                             ((arow * 128 + (kb * 32 + kgrp * 8) * 2) ^ ((arow & 7) << 4)));
#pragma unroll
      for (int nb = 0; nb < 4; nb++) {
        int wrow = nb * 16 + l15;
        H8 bb;
        bb.u = *(const u16x8*)((const char*)Wlds +
                               ((wrow * 128 + (kb * 32 + kgrp * 8) * 2) ^ ((wrow & 7) << 4)));
        acc[nb] = MFMA16(aa.h, bb.h, acc[nb]);
      }
    }
  }
#pragma unroll
  for (int nb = 0; nb < 4; nb++) {
#pragma unroll
    for (int r = 0; r < 4; r++) {
      out[(size_t)(m0 + wv * 16 + kgrp * 4 + r) * 1024 + n0 + nb * 16 + l15] = acc[nb][r];
    }
  }
}

extern "C" void kernel_launch(void* const* d_in, const int* in_sizes, int n_in,
                              void* d_out, int out_size, void* d_ws, size_t ws_size,
                              hipStream_t stream) {
  const float* q = (const float*)d_in[0];
  const float* k = (const float*)d_in[1];
  const float* v = (const float*)d_in[2];
  const float* w = (const float*)d_in[3];
  const int* smask = (const int*)d_in[5];
  float* out = (float*)d_out;

  char* ws = (char*)d_ws;
  int* lengths = (int*)ws;                                           // 16 B
  unsigned short* w_h = (unsigned short*)(ws + 256);                 // 2 MB
  unsigned short* attn_h = (unsigned short*)(ws + 256 + 2 * 1024 * 1024);  // 8 MB

  hipLaunchKernelGGL(prep_kernel, dim3(1028), dim3(256), 0, stream, w, smask, w_h, lengths);
  hipLaunchKernelGGL(attn_kernel, dim3(16, 64), dim3(256), 0, stream, q, k, v, lengths, attn_h);
  hipLaunchKernelGGL(merge_kernel, dim3(16, 64), dim3(256), 0, stream, attn_h, w_h, out);
}